// Round 7
// baseline (491.452 us; speedup 1.0000x reference)
//
#include <hip/hip_runtime.h>
#include <stdint.h>

#define R 128
#define NB 64

// workspace float offsets (total 4,341,760 floats ~= 16.6 MiB)
#define CAM1_OFF  0          // 8192*196 = 1605632 (fp32 atomic accum, zeroed)
#define CAM2_OFF  1605632    // 8192*49  = 401408  (fp32 atomic accum, zeroed)
#define POOL0_OFF 2007040    // 8192*196 (pooled cam0, UNnormalized)
#define POOL1_OFF 3612672    // 8192*49  (pooled cam1, UNnormalized)
#define WB_OFF    4014080    // 458752 bf16 = 229376 float slots
#define ACCS_OFF  4243456    // 3*8192 row sums      (zeroed; lvl0 uses)
#define ACCQ_OFF  4268032    // 3*8192 row sumsq     (zeroed; lvl0 uses)
#define PSQ_OFF   4292608    // 2*8192 pooled sumsq  (zeroed; lvl0 uses)
#define INVHI_OFF 4308992    // 2*8192 1/||cam row|| (cam1, cam2)
#define INVLO_OFF 4325376    // 2*8192 (1/64)/||pool row|| (pool0, pool1)

typedef __bf16 bf16;
typedef bf16 v2bf __attribute__((ext_vector_type(2)));
typedef bf16 v8bf __attribute__((ext_vector_type(8)));
typedef float f4v __attribute__((ext_vector_type(4)));

// lgkm-only barrier: keeps global loads in flight across the barrier
#define ASM_BARRIER() asm volatile("s_waitcnt lgkmcnt(0)\n\ts_barrier" ::: "memory")

// ---------------- prep: w->bf16, zero cam1/cam2 + accumulators + link out ---
__global__ void prep_w(const float* __restrict__ w0, const float* __restrict__ w1,
                       const float* __restrict__ w2, bf16* __restrict__ wb,
                       float* __restrict__ ws, float* __restrict__ out) {
    int id = blockIdx.x * 256 + threadIdx.x;   // grid 7840 -> 2007040 exact
    ws[id] = 0.f;                              // cam1+cam2 region [0, 2007040)
    if (id < 65536) ws[ACCS_OFF + id] = 0.f;   // accS+accQ+psq
    if (id < 32768) out[49152 + id] = 0.f;     // link outputs (atomicAdd targets)
    if (id < 458752) {
        float v;
        if (id < 65536)       v = w0[id];
        else if (id < 196608) v = w1[id - 65536];
        else                  v = w2[id - 196608];
        wb[id] = (bf16)v;
    }
}

// ---------------- cam GEMM fused: cam[b,r,i] = sum_c w[r,c]*fmap[b,c,i] -----
// 512 threads (8 waves 32m x 32n), BM=128 BN=64 BK=64, both operands staged to
// double-buffered LDS (comp() has zero global loads), depth-4 reg prefetch,
// lgkm-only barrier per K-iter.
// K-SPLIT: every block does exactly 8 K-iters (K-chunk=512). lvl2: 4 splits,
// lvl1: 2 splits -> split levels atomicAdd partial tiles into fp32 cam1/cam2;
// their stats/pool move to post_k. lvl0 (no split) keeps the fused epilogue
// (stats + 2x2 pool + pooled-sumsq atomics); cam0 never materialized.
__global__ __launch_bounds__(512) void cam_gemm(
    const float* __restrict__ f0, const float* __restrict__ f1,
    const float* __restrict__ f2, const bf16* __restrict__ wb,
    float* __restrict__ ws) {
    // layout: B bufs [0, 18432), A bufs [18432, 55296); epilogue f32 tile
    // (34816 B) reuses [0, 34816) after a __syncthreads.
    __shared__ __align__(16) char ldsRaw[55296];
#define LBUFB(u) ((bf16*)(ldsRaw + (u) * 9216))
#define LBUFA(u) ((bf16*)(ldsRaw + 18432 + (u) * 18432))

    int bid = blockIdx.x, tid = threadIdx.x;
    int lvl, b, i0, VW, kb;
    if (bid < 256)      { lvl = 2; b = bid >> 2; kb = (bid & 3) * 512;
                          i0 = 0; VW = 49; }                        // slowest first
    else if (bid < 768) { int t = bid - 256; lvl = 1; b = t >> 3; int r = t & 7;
                          int ti = r >> 1; kb = (r & 1) * 512;
                          i0 = ti * 56; VW = ti < 3 ? 56 : 28; }
    else                { int t = bid - 768; lvl = 0; b = t / 14;
                          int ti = t - b * 14; kb = 0; i0 = ti * 56; VW = 56; }
    const int C  = (lvl == 0) ? 512 : (lvl == 1) ? 1024 : 2048;
    const int HW = (lvl == 0) ? 784 : (lvl == 1) ? 196  : 49;
    const float* fmap = (lvl == 0) ? f0 : (lvl == 1) ? f1 : f2;
    const bf16*  wbl  = wb + ((lvl == 0) ? 0 : (lvl == 1) ? 65536 : 196608);

    // ---- B staging decode: 1 unit/thread; unit = 2 k-rows x 4 i ----
    int d = tid >> 4;                 // k-pair id 0..31
    int ku2 = d * 2;
    int i4 = (tid & 15) * 4;
    int i4eff = min(i4, VW - 4);      // clamp keeps float4 loads in-row
    int gbase = b * C * HW + (kb + ku2) * HW + i0 + i4eff;
    int ldsd[4];
    int i4c[4];
#pragma unroll
    for (int e = 0; e < 4; ++e) {
        int i = i4 + e;               // LDS row (n-local)
        int grp = (d >> 2) ^ ((i >> 3) & 7);
        ldsd[e] = i * 72 + grp * 8 + (d & 3) * 2;   // bf16 units
        i4c[e] = min(i, 48);          // clamp for HW==49 path
    }
    // ---- A staging decode: 32 B/thread = 2 chunks of one m-row ----
    int am = tid >> 2;                // 0..127 (m row)
    int akb = (tid & 3) * 16;         // bf16 k-offset within BK
    const bf16* awsrc = wbl + am * C + kb + akb;
    int axor = (am >> 3) & 7;
    int ac0 = (tid & 3) * 2;
    int aldsd0 = am * 72 + ((ac0    ) ^ axor) * 8;
    int aldsd1 = am * 72 + ((ac0 + 1) ^ axor) * 8;

    const int lane = tid & 63, wave = tid >> 6;
    const int lm = lane & 15, q = lane >> 4;
    const int wm = (wave >> 1) * 32, wn = (wave & 1) * 32;
    int irow[2], ixor[2];
#pragma unroll
    for (int sn = 0; sn < 2; ++sn) {
        irow[sn] = wn + sn * 16 + lm;
        ixor[sn] = (irow[sn] >> 3) & 7;
    }
    int arowl[2], axorl[2];
#pragma unroll
    for (int sm = 0; sm < 2; ++sm) {
        arowl[sm] = wm + sm * 16 + lm;
        axorl[sm] = (arowl[sm] >> 3) & 7;
    }

    auto loadT = [&](int kc, float4 (&r)[2]) {
        if (lvl != 2) {
            const float* p = fmap + gbase + kc * HW;
            r[0] = *(const float4*)p;
            r[1] = *(const float4*)(p + HW);
        } else {
            const float* p = fmap + b * C * 49 + (kb + kc + ku2) * 49;
            r[0].x = p[i4c[0]]; r[0].y = p[i4c[1]];
            r[0].z = p[i4c[2]]; r[0].w = p[i4c[3]];
            r[1].x = p[49 + i4c[0]]; r[1].y = p[49 + i4c[1]];
            r[1].z = p[49 + i4c[2]]; r[1].w = p[49 + i4c[3]];
        }
    };
    auto loadW = [&](int kc, v8bf (&w)[2]) {
        w[0] = *(const v8bf*)(awsrc + kc);
        w[1] = *(const v8bf*)(awsrc + kc + 8);
    };
    auto stage = [&](float4 (&r)[2], v8bf (&w)[2], bf16* bufB, bf16* bufA) {
        v2bf t0 = { (bf16)r[0].x, (bf16)r[1].x };
        v2bf t1 = { (bf16)r[0].y, (bf16)r[1].y };
        v2bf t2 = { (bf16)r[0].z, (bf16)r[1].z };
        v2bf t3 = { (bf16)r[0].w, (bf16)r[1].w };
        *(v2bf*)&bufB[ldsd[0]] = t0;
        *(v2bf*)&bufB[ldsd[1]] = t1;
        *(v2bf*)&bufB[ldsd[2]] = t2;
        *(v2bf*)&bufB[ldsd[3]] = t3;
        *(v8bf*)&bufA[aldsd0] = w[0];
        *(v8bf*)&bufA[aldsd1] = w[1];
    };

    f4v acc[2][2] = {};
    auto comp = [&](const bf16* bufB, const bf16* bufA) {
#pragma unroll
        for (int ks = 0; ks < 64; ks += 32) {
            int cq = (ks >> 3) + q;
            v8bf af[2];
#pragma unroll
            for (int sm = 0; sm < 2; ++sm)
                af[sm] = *(const v8bf*)&bufA[arowl[sm] * 72 + (cq ^ axorl[sm]) * 8];
            v8bf bfr[2];
#pragma unroll
            for (int sn = 0; sn < 2; ++sn)
                bfr[sn] = *(const v8bf*)&bufB[irow[sn] * 72 + (cq ^ ixor[sn]) * 8];
#pragma unroll
            for (int sm = 0; sm < 2; ++sm)
#pragma unroll
                for (int sn = 0; sn < 2; ++sn)
                    acc[sm][sn] = __builtin_amdgcn_mfma_f32_16x16x32_bf16(
                        af[sm], bfr[sn], acc[sm][sn], 0, 0, 0);
        }
    };

    // 8 K-iters per block (K-chunk = 512), depth-4 prefetch
    float4 rT[4][2];
    v8bf   rW[4][2];
    loadT(0, rT[0]);   loadW(0, rW[0]);
    loadT(64, rT[1]);  loadW(64, rW[1]);
    loadT(128, rT[2]); loadW(128, rW[2]);
    loadT(192, rT[3]); loadW(192, rW[3]);
    for (int t = 0; t < 8; t += 4) {
#pragma unroll
        for (int u = 0; u < 4; ++u) {
            stage(rT[u], rW[u], LBUFB(u & 1), LBUFA(u & 1));
            ASM_BARRIER();
            if (t + u + 4 < 8) { loadT((t + u + 4) << 6, rT[u]);
                                 loadW((t + u + 4) << 6, rW[u]); }
            comp(LBUFB(u & 1), LBUFA(u & 1));
        }
    }

    // ---- epilogue: acc -> LDS f32 tile [128][68] ----
    __syncthreads();                          // staging buffers done
    float* tile = (float*)ldsRaw;
#pragma unroll
    for (int sn = 0; sn < 2; ++sn)
#pragma unroll
        for (int sm = 0; sm < 2; ++sm)
#pragma unroll
            for (int reg = 0; reg < 4; ++reg)
                tile[(wm + sm * 16 + q * 4 + reg) * 68 + wn + sn * 16 + lm] =
                    acc[sm][sn][reg];
    __syncthreads();

    int row = tid >> 2, seg = tid & 3;        // 128 rows x 4 col-segments
    long grow = (long)b * 128 + row;
    const float* trow = tile + row * 68;
    if (lvl == 0) {
        // fused stats + 2x2 pool (tile = 2 input rows of 28, pooled row ti)
        float s = 0.f, qq = 0.f;
        const f4v* tr4 = (const f4v*)(trow + seg * 16);
#pragma unroll
        for (int g = 0; g < 4; ++g) {
            f4v v4 = tr4[g];
#pragma unroll
            for (int e = 0; e < 4; ++e) {
                int col = seg * 16 + g * 4 + e;
                if (col < 56) { float v = v4[e]; s += v; qq += v * v; }
            }
        }
        s += __shfl_xor(s, 1);  s += __shfl_xor(s, 2);
        qq += __shfl_xor(qq, 1); qq += __shfl_xor(qq, 2);
        if (seg == 0) {
            atomicAdd(&ws[ACCS_OFF + grow], s);
            atomicAdd(&ws[ACCQ_OFF + grow], qq);
        }
        float ps = 0.f;
        float* prow = ws + POOL0_OFF + grow * 196 + (i0 / 56) * 14;
        for (int j = seg; j < 14; j += 4) {
            float v = 0.25f * (trow[2 * j] + trow[2 * j + 1] +
                               trow[28 + 2 * j] + trow[28 + 2 * j + 1]);
            prow[j] = v; ps += v * v;
        }
        ps += __shfl_xor(ps, 1); ps += __shfl_xor(ps, 2);
        if (seg == 0) atomicAdd(&ws[PSQ_OFF + grow], ps);
    } else {
        // K-split partial: atomic accumulate into fp32 cam
        float* camrow = (lvl == 1) ? ws + CAM1_OFF + grow * 196 + i0
                                   : ws + CAM2_OFF + grow * 49;
        const f4v* tr4 = (const f4v*)(trow + seg * 16);
#pragma unroll
        for (int g = 0; g < 4; ++g) {
            f4v v4 = tr4[g];
#pragma unroll
            for (int e = 0; e < 4; ++e) {
                int col = seg * 16 + g * 4 + e;
                if (col < VW) atomicAdd(&camrow[col], v4[e]);
            }
        }
    }
#undef LBUFB
#undef LBUFA
}

// ---------------- post: lvl1/lvl2 stats + pool1 + all inv-norms, lvl0 final -
__global__ __launch_bounds__(256) void post_k(
    float* __restrict__ ws, const float* __restrict__ b0,
    const float* __restrict__ b1, const float* __restrict__ b2,
    float* __restrict__ out) {
    __shared__ float plds[4 * 196];
    int gw = blockIdx.x * 4 + (threadIdx.x >> 6);  // grid 6144 -> 24576
    int lane = threadIdx.x & 63;
    int lvl = gw >> 13, row = gw & 8191;           // row = b*128 + r
    if (lvl == 0) {
        if (lane == 0) {
            float s = ws[ACCS_OFF + row], qq = ws[ACCQ_OFF + row];
            float mean = s / 784.f;
            out[row] = mean + b0[row & 127];
            out[24576 + row] = sqrtf(fmaxf(qq - s * mean, 0.f) / 783.f);
            float qn = ws[PSQ_OFF + row];
            ws[INVLO_OFF + row] = (1.0f / 64.0f) / fmaxf(sqrtf(qn), 1e-12f);
        }
        return;
    }
    const int HW = (lvl == 1) ? 196 : 49;
    const float* cam = ws + ((lvl == 1) ? CAM1_OFF : CAM2_OFF) + (long)row * HW;
    float* myl = plds + (threadIdx.x >> 6) * 196;
    float s = 0.f, qq = 0.f;
    for (int j = lane; j < HW; j += 64) {
        float v = cam[j]; s += v; qq += v * v;
        if (lvl == 1) myl[j] = v;
    }
#pragma unroll
    for (int o = 32; o; o >>= 1) { s += __shfl_xor(s, o); qq += __shfl_xor(qq, o); }
    if (lane == 0) {
        float HWf = (float)HW;
        float mean = s / HWf;
        const float* bias = (lvl == 1) ? b1 : b2;
        out[lvl * 8192 + row] = mean + bias[row & 127];
        out[24576 + lvl * 8192 + row] = sqrtf(fmaxf(qq - s * mean, 0.f) / (HWf - 1.f));
        ws[INVHI_OFF + (lvl - 1) * 8192 + row] = 1.0f / fmaxf(sqrtf(qq), 1e-12f);
    }
    if (lvl == 1) {
        // 2x2 pool 14x14 -> 7x7 (same-wave LDS, no barrier needed)
        float ps = 0.f;
        if (lane < 49) {
            int oh = lane / 7, ow = lane - oh * 7;
            int ii = oh * 28 + ow * 2;
            float v = 0.25f * (myl[ii] + myl[ii + 1] + myl[ii + 14] + myl[ii + 15]);
            ws[POOL1_OFF + (long)row * 49 + lane] = v;
            ps = v * v;
        }
#pragma unroll
        for (int o = 32; o; o >>= 1) ps += __shfl_xor(ps, o);
        if (lane == 0)
            ws[INVLO_OFF + 8192 + row] = (1.0f / 64.0f) / fmaxf(sqrtf(ps), 1e-12f);
    }
}

// ---------------- link via MFMA, atomicAdd into out (no part buffer) -------
__device__ inline v8bf load_frag8(const float* __restrict__ row, int k0, int K) {
    v8bf f;
    if (k0 + 8 <= K && (K & 3) == 0) {
        float4 a = *(const float4*)(row + k0);
        float4 c = *(const float4*)(row + k0 + 4);
        f[0] = (bf16)a.x; f[1] = (bf16)a.y; f[2] = (bf16)a.z; f[3] = (bf16)a.w;
        f[4] = (bf16)c.x; f[5] = (bf16)c.y; f[6] = (bf16)c.z; f[7] = (bf16)c.w;
    } else {
#pragma unroll
        for (int j = 0; j < 8; ++j)
            f[j] = (k0 + j < K) ? (bf16)row[k0 + j] : (bf16)0.f;
    }
    return f;
}

// block per (lk, b, m-half): 64m x 128n. Both inv-norms (and 1/B) applied
// here; partials atomicAdd'ed straight into out[49152..].
__global__ __launch_bounds__(256) void link_mfma_k(const float* __restrict__ ws,
                                                   float* __restrict__ out) {
    int bid = blockIdx.x, tid = threadIdx.x;
    int lk = bid >> 7, rem = bid & 127;
    int b = rem >> 1, mh = rem & 1;
    const int K = lk ? 49 : 196;
    const float* lo = ws + (lk ? POOL1_OFF : POOL0_OFF) + (long)(b * 128 + mh * 64) * K;
    const float* hi = ws + (lk ? CAM2_OFF : CAM1_OFF) + (long)b * 128 * K;
    const float* ihi = ws + INVHI_OFF + lk * 8192 + b * 128;
    const float* ilo = ws + INVLO_OFF + lk * 8192 + b * 128 + mh * 64;
    int lane = tid & 63, wv = tid >> 6;
    int lm = lane & 15, q = lane >> 4;
    int wm = (wv >> 1) * 32, wn = (wv & 1) * 64;
    f4v acc[2][4] = {};
    for (int kc = 0; kc < K; kc += 32) {
        v8bf af[2], bff[4];
#pragma unroll
        for (int sm = 0; sm < 2; ++sm)
            af[sm] = load_frag8(lo + (long)(wm + sm * 16 + lm) * K, kc + q * 8, K);
#pragma unroll
        for (int sn = 0; sn < 4; ++sn)
            bff[sn] = load_frag8(hi + (long)(wn + sn * 16 + lm) * K, kc + q * 8, K);
#pragma unroll
        for (int sm = 0; sm < 2; ++sm)
#pragma unroll
            for (int sn = 0; sn < 4; ++sn)
                acc[sm][sn] = __builtin_amdgcn_mfma_f32_16x16x32_bf16(
                    af[sm], bff[sn], acc[sm][sn], 0, 0, 0);
    }
    float fl[2][4];
#pragma unroll
    for (int sm = 0; sm < 2; ++sm)
#pragma unroll
        for (int reg = 0; reg < 4; ++reg)
            fl[sm][reg] = ilo[wm + sm * 16 + q * 4 + reg];
    float* ob = out + 49152 + lk * 16384;
#pragma unroll
    for (int sn = 0; sn < 4; ++sn) {
        int n = wn + sn * 16 + lm;
        float sh = ihi[n];
#pragma unroll
        for (int sm = 0; sm < 2; ++sm) {
#pragma unroll
            for (int reg = 0; reg < 4; ++reg) {
                int m = mh * 64 + wm + sm * 16 + q * 4 + reg;
                atomicAdd(&ob[m * 128 + n], acc[sm][sn][reg] * sh * fl[sm][reg]);
            }
        }
    }
}

extern "C" void kernel_launch(void* const* d_in, const int* in_sizes, int n_in,
                              void* d_out, int out_size, void* d_ws, size_t ws_size,
                              hipStream_t stream) {
    const float* f0 = (const float*)d_in[0];
    const float* w0 = (const float*)d_in[1];
    const float* b0 = (const float*)d_in[2];
    const float* f1 = (const float*)d_in[3];
    const float* w1 = (const float*)d_in[4];
    const float* b1 = (const float*)d_in[5];
    const float* f2 = (const float*)d_in[6];
    const float* w2 = (const float*)d_in[7];
    const float* b2 = (const float*)d_in[8];
    float* ws = (float*)d_ws;
    float* out = (float*)d_out;
    bf16* wb = (bf16*)(ws + WB_OFF);

    prep_w<<<7840, 256, 0, stream>>>(w0, w1, w2, wb, ws, out);
    cam_gemm<<<1664, 512, 0, stream>>>(f0, f1, f2, wb, ws);
    post_k<<<6144, 256, 0, stream>>>(ws, b0, b1, b2, out);
    link_mfma_k<<<256, 256, 0, stream>>>(ws, out);
}